// Round 8
// baseline (113.914 us; speedup 1.0000x reference)
//
#include <hip/hip_runtime.h>
#include <math.h>

#define BOUND 3.0f
#define LOG2E 1.4426950408889634f
#define LN2 0.6931471805599453f
#define CINV 0.17806267806267807f   /* 1/5.616 */

typedef _Float16 half8 __attribute__((ext_vector_type(8)));
typedef _Float16 half4 __attribute__((ext_vector_type(4)));
typedef _Float16 half2v __attribute__((ext_vector_type(2)));
typedef float f32x4 __attribute__((ext_vector_type(4)));

__device__ __forceinline__ float fexp2(float x) { return __builtin_amdgcn_exp2f(x); }
__device__ __forceinline__ float flog2(float x) { return __builtin_amdgcn_logf(x); }
__device__ __forceinline__ float frcp(float x)  { return __builtin_amdgcn_rcpf(x); }

__device__ __forceinline__ float hsum2(half2v a, float c) {
    const half2v ones = {(_Float16)1.f, (_Float16)1.f};
    return __builtin_amdgcn_fdot2(a, ones, c, false);
}

// A-fragments for transposed GEMM C[param][elem], 16x16x32 f16.
// aW3[m][l][t] = W3[8*(l>>4)+t][16m + (l&15)] * (m<8 ? LOG2E : 1)
__global__ void prep_kernel(const float* __restrict__ W2, const float* __restrict__ W3,
                            const float* __restrict__ b3,
                            _Float16* __restrict__ aW2, _Float16* __restrict__ aW3,
                            float* __restrict__ b3s) {
    int tid = blockIdx.x * blockDim.x + threadIdx.x;
    int nth = gridDim.x * blockDim.x;
    for (int i = tid; i < 16 * 64 * 8; i += nth) {
        int t = i & 7, l = (i >> 3) & 63, m = i >> 9;
        int k = 8 * (l >> 4) + t, col = 16 * m + (l & 15);
        float v = (col < 255) ? W3[k * 255 + col] : 0.f;
        if (m < 8) v *= LOG2E;
        aW3[i] = (_Float16)v;
    }
    for (int i = tid; i < 2 * 64 * 8; i += nth) {
        int t = i & 7, l = (i >> 3) & 63, m = i >> 9;
        int k = 8 * (l >> 4) + t, col = 16 * m + (l & 15);
        aW2[i] = (_Float16)W2[k * 32 + col];
    }
    for (int i = tid; i < 255; i += nth)
        b3s[i] = b3[i] * ((i < 128) ? LOG2E : 1.f);
}

// 128-thread WG = 2 fully independent waves (disjoint 8KB LDS halves, no
// barriers). __launch_bounds__(128,5): 5 waves/EU = 20 waves/CU = 10 WGs
// x 16KB = 160KB LDS — EXACTLY satisfiable, so the compiler must honor it
// and cap VGPR <= ~102. (R7's (128,8) was unsatisfiable -> constraint
// dropped -> 108 VGPR -> occupancy collapse. R6's 64-thread WGs were
// capped at ~16 waves/CU by the WG-slot limit.)
__global__ __launch_bounds__(128, 5) void spline_kernel(
    const float* __restrict__ x_in, const float* __restrict__ cond_in,
    const float* __restrict__ W1, const float* __restrict__ b1,
    const float* __restrict__ b2, const float* __restrict__ b3s,
    const _Float16* __restrict__ aW2, const _Float16* __restrict__ aW3,
    float* __restrict__ out, int N) {

    //  f32 view: 64 rows x 32 f32 (128B rows, 8 granules, XOR-swizzled)
    //  f16 view: 64 rows x 64 halves (128B rows, 8 granules, XOR-swizzled)
    __shared__ float sbuf[2][64 * 32];

    const int tid = threadIdx.x;
    const int w = tid >> 6;
    const int l = tid & 63;
    const int j = l & 15, g = l >> 4;
    const int sx = l & 7;
    const int ksw = j & 7;
    const int gown = blockIdx.x * 128 + tid;
    const int ic = (gown < N) ? gown : (N - 1);

    float* buf = sbuf[w];
    _Float16* bufh = (_Float16*)sbuf[w];

    float cx = cond_in[ic];
    float x = x_in[ic];

    // ---------------- Phase 1: h1 B-fragments (rank-1) --------------------
    float4 w1a = *(const float4*)(W1 + 8 * g);
    float4 w1b = *(const float4*)(W1 + 8 * g + 4);
    float4 b1a = *(const float4*)(b1 + 8 * g);
    float4 b1b = *(const float4*)(b1 + 8 * g + 4);

    half8 h1hi[4], h1lo[4];
#pragma unroll
    for (int n = 0; n < 4; n++) {
        float c = __shfl(cx, 16 * n + j, 64);
        float h[8];
        h[0] = fmaxf(fmaf(c, w1a.x, b1a.x), 0.f);
        h[1] = fmaxf(fmaf(c, w1a.y, b1a.y), 0.f);
        h[2] = fmaxf(fmaf(c, w1a.z, b1a.z), 0.f);
        h[3] = fmaxf(fmaf(c, w1a.w, b1a.w), 0.f);
        h[4] = fmaxf(fmaf(c, w1b.x, b1b.x), 0.f);
        h[5] = fmaxf(fmaf(c, w1b.y, b1b.y), 0.f);
        h[6] = fmaxf(fmaf(c, w1b.z, b1b.z), 0.f);
        h[7] = fmaxf(fmaf(c, w1b.w, b1b.w), 0.f);
#pragma unroll
        for (int t = 0; t < 8; t++) {
            _Float16 hi = (_Float16)h[t];
            h1hi[n][t] = hi;
            h1lo[n][t] = (_Float16)(h[t] - (float)hi);
        }
    }

    // ---------------- Phase 2: MLP2 via MFMA, split h2 -> LDS (f16) -------
    half8 a2[2];
    a2[0] = *(const half8*)(aW2 + (0 * 64 + l) * 8);
    a2[1] = *(const half8*)(aW2 + (1 * 64 + l) * 8);

#pragma unroll
    for (int m = 0; m < 2; m++) {
        float4 bb = *(const float4*)(b2 + 16 * m + 4 * g);
        f32x4 binit = {bb.x, bb.y, bb.z, bb.w};
#pragma unroll
        for (int n = 0; n < 4; n++) {
            f32x4 acc = binit;
            acc = __builtin_amdgcn_mfma_f32_16x16x32_f16(a2[m], h1lo[n], acc, 0, 0, 0);
            acc = __builtin_amdgcn_mfma_f32_16x16x32_f16(a2[m], h1hi[n], acc, 0, 0, 0);
            float v0 = fmaxf(acc[0], 0.f), v1 = fmaxf(acc[1], 0.f);
            float v2 = fmaxf(acc[2], 0.f), v3 = fmaxf(acc[3], 0.f);
            _Float16 p0 = (_Float16)v0, p1 = (_Float16)v1, p2 = (_Float16)v2, p3 = (_Float16)v3;
            half4 hv = {p0, p1, p2, p3};
            half4 lv = {(_Float16)(v0 - (float)p0), (_Float16)(v1 - (float)p1),
                        (_Float16)(v2 - (float)p2), (_Float16)(v3 - (float)p3)};
            int rb = (16 * n + j) * 64;
            *(half4*)(bufh + rb + (((2 * m + (g >> 1)) ^ ksw) << 3) + ((g & 1) << 2)) = hv;
            *(half4*)(bufh + rb + (((4 + 2 * m + (g >> 1)) ^ ksw) << 3) + ((g & 1) << 2)) = lv;
        }
    }

    // ---------------- Phase 3: h2 B-fragments -----------------------------
    half8 bhi[4], blo[4];
#pragma unroll
    for (int n = 0; n < 4; n++) {
        int rb = (16 * n + j) * 64;
        bhi[n] = *(const half8*)(bufh + rb + ((g ^ ksw) << 3));
        blo[n] = *(const half8*)(bufh + rb + (((4 + g) ^ ksw) << 3));
    }

    bool inside = (x >= -BOUND) && (x <= BOUND);
    float xc = fminf(fmaxf(x, -BOUND), BOUND);

    // ---------------- Phase 4: W logits -> exp2 -> LDS (f32, 2 rounds) ----
    f32x4 wv[16];
#pragma unroll
    for (int s = 0; s < 2; s++) {
#pragma unroll
        for (int mm = 0; mm < 2; mm++) {
            int m = 2 * s + mm;
            half8 a = *(const half8*)(aW3 + (m * 64 + l) * 8);
            float4 bb = *(const float4*)(b3s + 16 * m + 4 * g);
            f32x4 binit = {bb.x, bb.y, bb.z, bb.w};
#pragma unroll
            for (int n = 0; n < 4; n++) {
                f32x4 acc = binit;
                acc = __builtin_amdgcn_mfma_f32_16x16x32_f16(a, blo[n], acc, 0, 0, 0);
                acc = __builtin_amdgcn_mfma_f32_16x16x32_f16(a, bhi[n], acc, 0, 0, 0);
                f32x4 e = {fexp2(acc[0]), fexp2(acc[1]), fexp2(acc[2]), fexp2(acc[3])};
                *(f32x4*)(buf + (16 * n + j) * 32 + (((4 * mm + g) ^ ksw) << 2)) = e;
            }
        }
#pragma unroll
        for (int t = 0; t < 8; t++)
            wv[8 * s + t] = *(const f32x4*)(buf + l * 32 + ((t ^ sx) << 2));
    }

    // ---------------- Phase 5: hierarchical W scan (f32-exact) ------------
    int idx; float idxf, xk, wk;
    {
        float G[16];
        float run = 0.f;
#pragma unroll
        for (int t = 0; t < 16; t++) {
            run += (wv[t][0] + wv[t][1]) + (wv[t][2] + wv[t][3]);
            G[t] = run;
        }
        float tot = G[15];
        float rcptot = frcp(tot);
        float rr = (xc + BOUND) * tot * CINV;
        float dr1 = 0.0010683761f * tot;
        float dr4 = 4.f * dr1;
        float r = rr, Gsel = 0.f;
        int qidx = 0;
#pragma unroll
        for (int t = 0; t < 15; t++) {
            r -= dr4;
            bool c = (G[t] <= r);
            qidx += c ? 1 : 0;
            Gsel = c ? G[t] : Gsel;
        }
        f32x4 fv = wv[0];
#pragma unroll
        for (int t = 1; t < 16; t++) fv = (qidx == t) ? wv[t] : fv;
        float e0 = fv[0], e1 = fv[1], e2 = fv[2], e3 = fv[3];
        float qf = (float)qidx;
        float rq = fmaf(-qf, dr4, rr);
        float p1 = Gsel + e0, p2 = p1 + e1, p3 = p2 + e2;
        bool c1 = (p1 <= rq - dr1);
        bool c2 = (p2 <= fmaf(-2.f, dr1, rq));
        bool c3 = (p3 <= fmaf(-3.f, dr1, rq));
        idx = 4 * qidx + (c1 ? 1 : 0) + (c2 ? 1 : 0) + (c3 ? 1 : 0);
        float Pk = c1 ? p1 : Gsel; Pk = c2 ? p2 : Pk; Pk = c3 ? p3 : Pk;
        float ek = c1 ? e1 : e0;   ek = c2 ? e2 : ek; ek = c3 ? e3 : ek;
        idxf = (float)idx;
        xk = fmaf(0.006f, idxf, -BOUND) + 5.616f * Pk * rcptot;
        wk = fmaf(5.616f * rcptot, ek, 0.006f);
        wk = (idx == 63) ? (BOUND - xk) : wk;
    }

    // ---------------- Phase 6: H logits -> exp2 -> LDS (f16, 1-term) ------
#pragma unroll
    for (int m = 0; m < 4; m++) {
        half8 a = *(const half8*)(aW3 + ((m + 4) * 64 + l) * 8);
        float4 bb = *(const float4*)(b3s + 64 + 16 * m + 4 * g);
        f32x4 binit = {bb.x, bb.y, bb.z, bb.w};
#pragma unroll
        for (int n = 0; n < 4; n++) {
            f32x4 acc = binit;
            acc = __builtin_amdgcn_mfma_f32_16x16x32_f16(a, bhi[n], acc, 0, 0, 0);
            half4 e = {(_Float16)fexp2(acc[0]), (_Float16)fexp2(acc[1]),
                       (_Float16)fexp2(acc[2]), (_Float16)fexp2(acc[3])};
            *(half4*)(bufh + (16 * n + j) * 64 +
                      (((2 * m + (g >> 1)) ^ ksw) << 3) + ((g & 1) << 2)) = e;
        }
    }

    // ---------------- Phase 7: H selection (fdot2 group sums) -------------
    float yk, hk;
    {
        int qh = idx >> 2, rh = idx & 3;
        float toth = 0.f, Gq = 0.f;
#pragma unroll
        for (int t = 0; t < 8; t++) {
            half8 hv = *(const half8*)(bufh + l * 64 + ((t ^ sx) << 3));
            half2v* hp = (half2v*)&hv;
            float gs0 = hsum2(hp[0], hsum2(hp[1], 0.f));
            float gs1 = hsum2(hp[2], hsum2(hp[3], 0.f));
            toth += gs0 + gs1;
            Gq += (2 * t < qh) ? gs0 : 0.f;
            Gq += (2 * t + 1 < qh) ? gs1 : 0.f;
        }
        half4 fv = *(const half4*)(bufh + l * 64 + (((qh >> 1) ^ sx) << 3) + ((qh & 1) << 2));
        float f0 = (float)fv[0], f1 = (float)fv[1], f2 = (float)fv[2], f3 = (float)fv[3];
        float Sh = Gq;
        Sh += (rh >= 1) ? f0 : 0.f;
        Sh += (rh >= 2) ? f1 : 0.f;
        Sh += (rh >= 3) ? f2 : 0.f;
        float x01 = (rh & 1) ? f1 : f0;
        float x23 = (rh & 1) ? f3 : f2;
        float eidx = (rh & 2) ? x23 : x01;
        float chh = 5.616f * frcp(toth);
        yk = fmaf(0.006f, idxf, -BOUND) + chh * Sh;
        hk = fmaf(chh, eidx, 0.006f);
        hk = (idx == 63) ? (BOUND - yk) : hk;
    }

    // ---------------- Phase 8: D/L via MFMA, f32-staged, 4 rounds ---------
    // Round s stages params 128+32s .. 159+32s into the 8KB buffer.
    const int c0 = (idx > 0) ? (idx - 1) : 0;
    const int rc0a = (c0 < 32) ? c0 : 31;
    const int rc0b = (c0 >= 32) ? (c0 - 32) : 0;
    const int rc1a = (idx < 32) ? idx : 31;
    const int rc1b = (idx >= 32) ? (idx - 32) : 0;
    float v0a, v0b, v1a, v1b, vl191, vla, vlb;
#pragma unroll
    for (int s = 0; s < 4; s++) {
#pragma unroll
        for (int mm = 0; mm < 2; mm++) {
            half8 a = *(const half8*)(aW3 + ((8 + 2 * s + mm) * 64 + l) * 8);
#pragma unroll
            for (int n = 0; n < 4; n++) {
                f32x4 acc = {0.f, 0.f, 0.f, 0.f};
                acc = __builtin_amdgcn_mfma_f32_16x16x32_f16(a, bhi[n], acc, 0, 0, 0);
                *(f32x4*)(buf + (16 * n + j) * 32 + (((4 * mm + g) ^ ksw) << 2)) = acc;
            }
        }
        if (s == 0) {
            v0a = buf[l * 32 + (((rc0a >> 2) ^ sx) << 2) + (rc0a & 3)];
            v1a = buf[l * 32 + (((rc1a >> 2) ^ sx) << 2) + (rc1a & 3)];
        } else if (s == 1) {
            v0b = buf[l * 32 + (((rc0b >> 2) ^ sx) << 2) + (rc0b & 3)];
            v1b = buf[l * 32 + (((rc1b >> 2) ^ sx) << 2) + (rc1b & 3)];
            vl191 = buf[l * 32 + ((7 ^ sx) << 2) + 3];   // param 191 (col 31)
        } else if (s == 2) {
            vla = buf[l * 32 + (((rc0a >> 2) ^ sx) << 2) + (rc0a & 3)];
        } else {
            vlb = buf[l * 32 + (((rc0b >> 2) ^ sx) << 2) + (rc0b & 3)];
        }
    }
    float accd0 = ((c0 < 32) ? v0a : v0b) + b3s[127 + idx];
    float accd1 = ((idx < 32) ? v1a : v1b) + b3s[(idx < 63) ? (128 + idx) : 191];
    float lsel = (c0 < 32) ? vla : vlb;
    float accl = ((idx == 0) ? vl191 : lsel) + b3s[191 + idx];

    // ---------------- Phase 9: tail ---------------------------------------
    float e0t = fexp2(-fabsf(accd0) * LOG2E);
    float sp0 = fmaxf(accd0, 0.f) + LN2 * flog2(1.f + e0t);
    float e1t = fexp2(-fabsf(accd1) * LOG2E);
    float sp1 = fmaxf(accd1, 0.f) + LN2 * flog2(1.f + e1t);
    float d0 = (idx == 0)  ? 1.f : (0.001f + sp0);
    float d1 = (idx == 63) ? 1.f : (0.001f + sp1);
    float sig = frcp(1.f + fexp2(-accl * LOG2E));
    float lam = fmaf(0.95f, sig, 0.025f);

    float rwk = frcp(wk);
    float wb = sqrtf(d0 * frcp(d1));
    float wc = fmaf(lam, d0, (1.f - lam) * wb * d1) * wk * frcp(hk);
    float ya = yk, yb = yk + hk;
    float yc = fmaf(1.f - lam, ya, lam * wb * yb) * frcp(fmaf(lam, wb, 1.f - lam));
    float theta = (xc - xk) * rwk;
    bool left = theta <= lam;
    float num = left ? fmaf(ya, lam - theta, wc * yc * theta)
                     : fmaf(wc * yc, 1.f - theta, wb * yb * (theta - lam));
    float den = left ? fmaf(wc, theta, lam - theta)
                     : fmaf(wc, 1.f - theta, wb * (theta - lam));
    float y_in = num * frcp(den);
    float dnum = left ? (wc * lam * (yc - ya))
                      : (wb * wc * (1.f - lam) * (yb - yc));
    float ld_in = LN2 * (flog2(dnum) - 2.f * flog2(fabsf(den)) - flog2(wk));

    if (gown < N) {
        out[gown]     = inside ? y_in : x;
        out[N + gown] = inside ? ld_in : 0.f;
    }
}

extern "C" void kernel_launch(void* const* d_in, const int* in_sizes, int n_in,
                              void* d_out, int out_size, void* d_ws, size_t ws_size,
                              hipStream_t stream) {
    const float* x  = (const float*)d_in[0];
    const float* cx = (const float*)d_in[1];
    const float* W1 = (const float*)d_in[2];
    const float* b1 = (const float*)d_in[3];
    const float* W2 = (const float*)d_in[4];
    const float* b2 = (const float*)d_in[5];
    const float* W3 = (const float*)d_in[6];
    const float* b3 = (const float*)d_in[7];
    int N = in_sizes[0];

    _Float16* aW3 = (_Float16*)d_ws;          // 16*64*8 halves
    _Float16* aW2 = aW3 + 16 * 64 * 8;        // 1024 halves
    float* b3s = (float*)(aW2 + 2 * 64 * 8);  // 255 floats
    float* out = (float*)d_out;

    hipLaunchKernelGGL(prep_kernel, dim3(8), dim3(256), 0, stream, W2, W3, b3, aW2, aW3, b3s);
    hipLaunchKernelGGL(spline_kernel, dim3((N + 127) / 128), dim3(128), 0, stream,
                       x, cx, W1, b1, b2, b3s, aW2, aW3, out, N);
}

// Round 9
// 60.339 us; speedup vs baseline: 1.8879x; 1.8879x over previous
//
#include <hip/hip_runtime.h>
#include <math.h>

#define BOUND 3.0f
#define LOG2E 1.4426950408889634f
#define LN2 0.6931471805599453f
#define CINV 0.17806267806267807f   /* 1/5.616 */

typedef _Float16 half8 __attribute__((ext_vector_type(8)));
typedef _Float16 half4 __attribute__((ext_vector_type(4)));
typedef _Float16 half2v __attribute__((ext_vector_type(2)));
typedef float f32x4 __attribute__((ext_vector_type(4)));

__device__ __forceinline__ float fexp2(float x) { return __builtin_amdgcn_exp2f(x); }
__device__ __forceinline__ float flog2(float x) { return __builtin_amdgcn_logf(x); }
__device__ __forceinline__ float frcp(float x)  { return __builtin_amdgcn_rcpf(x); }

__device__ __forceinline__ float hsum2(half2v a, float c) {
    const half2v ones = {(_Float16)1.f, (_Float16)1.f};
    return __builtin_amdgcn_fdot2(a, ones, c, false);
}

// A-fragments for transposed GEMM C[param][elem], 16x16x32 f16.
// aW3[m][l][t] = W3[8*(l>>4)+t][16m + (l&15)] * (m<8 ? LOG2E : 1)
__global__ void prep_kernel(const float* __restrict__ W2, const float* __restrict__ W3,
                            const float* __restrict__ b3,
                            _Float16* __restrict__ aW2, _Float16* __restrict__ aW3,
                            float* __restrict__ b3s) {
    int tid = blockIdx.x * blockDim.x + threadIdx.x;
    int nth = gridDim.x * blockDim.x;
    for (int i = tid; i < 16 * 64 * 8; i += nth) {
        int t = i & 7, l = (i >> 3) & 63, m = i >> 9;
        int k = 8 * (l >> 4) + t, col = 16 * m + (l & 15);
        float v = (col < 255) ? W3[k * 255 + col] : 0.f;
        if (m < 8) v *= LOG2E;
        aW3[i] = (_Float16)v;
    }
    for (int i = tid; i < 2 * 64 * 8; i += nth) {
        int t = i & 7, l = (i >> 3) & 63, m = i >> 9;
        int k = 8 * (l >> 4) + t, col = 16 * m + (l & 15);
        aW2[i] = (_Float16)W2[k * 32 + col];
    }
    for (int i = tid; i < 255; i += nth)
        b3s[i] = b3[i] * ((i < 128) ? LOG2E : 1.f);
}

// 128-thread WG = 2 fully independent waves (disjoint 8KB LDS halves, no
// barriers). __launch_bounds__(128,4): 4 waves/EU = 16 waves/CU = 8 WGs
// x 16KB = 128KB LDS <= 160KB — satisfiable, and the VGPR ceiling (128)
// is above the body's natural usage, so NO spills.
// (R8 lesson: waves/EU hints must sit on the VGPR step values {8,4,2} ->
// VGPR {<=64,<=128,<=256}; asking for 5 forced <=64 and spilled to HBM.
// R6 lesson: 1-wave WGs are slot-capped (~11-16 WGs/CU) before LDS.)
__global__ __launch_bounds__(128, 4) void spline_kernel(
    const float* __restrict__ x_in, const float* __restrict__ cond_in,
    const float* __restrict__ W1, const float* __restrict__ b1,
    const float* __restrict__ b2, const float* __restrict__ b3s,
    const _Float16* __restrict__ aW2, const _Float16* __restrict__ aW3,
    float* __restrict__ out, int N) {

    //  f32 view: 64 rows x 32 f32 (128B rows, 8 granules, XOR-swizzled)
    //  f16 view: 64 rows x 64 halves (128B rows, 8 granules, XOR-swizzled)
    __shared__ float sbuf[2][64 * 32];

    const int tid = threadIdx.x;
    const int w = tid >> 6;
    const int l = tid & 63;
    const int j = l & 15, g = l >> 4;
    const int sx = l & 7;
    const int ksw = j & 7;
    const int gown = blockIdx.x * 128 + tid;
    const int ic = (gown < N) ? gown : (N - 1);

    float* buf = sbuf[w];
    _Float16* bufh = (_Float16*)sbuf[w];

    float cx = cond_in[ic];
    float x = x_in[ic];

    // ---------------- Phase 1: h1 B-fragments (rank-1) --------------------
    float4 w1a = *(const float4*)(W1 + 8 * g);
    float4 w1b = *(const float4*)(W1 + 8 * g + 4);
    float4 b1a = *(const float4*)(b1 + 8 * g);
    float4 b1b = *(const float4*)(b1 + 8 * g + 4);

    half8 h1hi[4], h1lo[4];
#pragma unroll
    for (int n = 0; n < 4; n++) {
        float c = __shfl(cx, 16 * n + j, 64);
        float h[8];
        h[0] = fmaxf(fmaf(c, w1a.x, b1a.x), 0.f);
        h[1] = fmaxf(fmaf(c, w1a.y, b1a.y), 0.f);
        h[2] = fmaxf(fmaf(c, w1a.z, b1a.z), 0.f);
        h[3] = fmaxf(fmaf(c, w1a.w, b1a.w), 0.f);
        h[4] = fmaxf(fmaf(c, w1b.x, b1b.x), 0.f);
        h[5] = fmaxf(fmaf(c, w1b.y, b1b.y), 0.f);
        h[6] = fmaxf(fmaf(c, w1b.z, b1b.z), 0.f);
        h[7] = fmaxf(fmaf(c, w1b.w, b1b.w), 0.f);
#pragma unroll
        for (int t = 0; t < 8; t++) {
            _Float16 hi = (_Float16)h[t];
            h1hi[n][t] = hi;
            h1lo[n][t] = (_Float16)(h[t] - (float)hi);
        }
    }

    // ---------------- Phase 2: MLP2 via MFMA, split h2 -> LDS (f16) -------
    half8 a2[2];
    a2[0] = *(const half8*)(aW2 + (0 * 64 + l) * 8);
    a2[1] = *(const half8*)(aW2 + (1 * 64 + l) * 8);

#pragma unroll
    for (int m = 0; m < 2; m++) {
        float4 bb = *(const float4*)(b2 + 16 * m + 4 * g);
        f32x4 binit = {bb.x, bb.y, bb.z, bb.w};
#pragma unroll
        for (int n = 0; n < 4; n++) {
            f32x4 acc = binit;
            acc = __builtin_amdgcn_mfma_f32_16x16x32_f16(a2[m], h1lo[n], acc, 0, 0, 0);
            acc = __builtin_amdgcn_mfma_f32_16x16x32_f16(a2[m], h1hi[n], acc, 0, 0, 0);
            float v0 = fmaxf(acc[0], 0.f), v1 = fmaxf(acc[1], 0.f);
            float v2 = fmaxf(acc[2], 0.f), v3 = fmaxf(acc[3], 0.f);
            _Float16 p0 = (_Float16)v0, p1 = (_Float16)v1, p2 = (_Float16)v2, p3 = (_Float16)v3;
            half4 hv = {p0, p1, p2, p3};
            half4 lv = {(_Float16)(v0 - (float)p0), (_Float16)(v1 - (float)p1),
                        (_Float16)(v2 - (float)p2), (_Float16)(v3 - (float)p3)};
            int rb = (16 * n + j) * 64;
            *(half4*)(bufh + rb + (((2 * m + (g >> 1)) ^ ksw) << 3) + ((g & 1) << 2)) = hv;
            *(half4*)(bufh + rb + (((4 + 2 * m + (g >> 1)) ^ ksw) << 3) + ((g & 1) << 2)) = lv;
        }
    }

    // ---------------- Phase 3: h2 B-fragments -----------------------------
    half8 bhi[4], blo[4];
#pragma unroll
    for (int n = 0; n < 4; n++) {
        int rb = (16 * n + j) * 64;
        bhi[n] = *(const half8*)(bufh + rb + ((g ^ ksw) << 3));
        blo[n] = *(const half8*)(bufh + rb + (((4 + g) ^ ksw) << 3));
    }

    bool inside = (x >= -BOUND) && (x <= BOUND);
    float xc = fminf(fmaxf(x, -BOUND), BOUND);

    // ---------------- Phase 4: W logits -> exp2 -> LDS (f32, 2 rounds) ----
    f32x4 wv[16];
#pragma unroll
    for (int s = 0; s < 2; s++) {
#pragma unroll
        for (int mm = 0; mm < 2; mm++) {
            int m = 2 * s + mm;
            half8 a = *(const half8*)(aW3 + (m * 64 + l) * 8);
            float4 bb = *(const float4*)(b3s + 16 * m + 4 * g);
            f32x4 binit = {bb.x, bb.y, bb.z, bb.w};
#pragma unroll
            for (int n = 0; n < 4; n++) {
                f32x4 acc = binit;
                acc = __builtin_amdgcn_mfma_f32_16x16x32_f16(a, blo[n], acc, 0, 0, 0);
                acc = __builtin_amdgcn_mfma_f32_16x16x32_f16(a, bhi[n], acc, 0, 0, 0);
                f32x4 e = {fexp2(acc[0]), fexp2(acc[1]), fexp2(acc[2]), fexp2(acc[3])};
                *(f32x4*)(buf + (16 * n + j) * 32 + (((4 * mm + g) ^ ksw) << 2)) = e;
            }
        }
#pragma unroll
        for (int t = 0; t < 8; t++)
            wv[8 * s + t] = *(const f32x4*)(buf + l * 32 + ((t ^ sx) << 2));
    }

    // ---------------- Phase 5: hierarchical W scan (f32-exact) ------------
    int idx; float idxf, xk, wk;
    {
        float G[16];
        float run = 0.f;
#pragma unroll
        for (int t = 0; t < 16; t++) {
            run += (wv[t][0] + wv[t][1]) + (wv[t][2] + wv[t][3]);
            G[t] = run;
        }
        float tot = G[15];
        float rcptot = frcp(tot);
        float rr = (xc + BOUND) * tot * CINV;
        float dr1 = 0.0010683761f * tot;
        float dr4 = 4.f * dr1;
        float r = rr, Gsel = 0.f;
        int qidx = 0;
#pragma unroll
        for (int t = 0; t < 15; t++) {
            r -= dr4;
            bool c = (G[t] <= r);
            qidx += c ? 1 : 0;
            Gsel = c ? G[t] : Gsel;
        }
        f32x4 fv = wv[0];
#pragma unroll
        for (int t = 1; t < 16; t++) fv = (qidx == t) ? wv[t] : fv;
        float e0 = fv[0], e1 = fv[1], e2 = fv[2], e3 = fv[3];
        float qf = (float)qidx;
        float rq = fmaf(-qf, dr4, rr);
        float p1 = Gsel + e0, p2 = p1 + e1, p3 = p2 + e2;
        bool c1 = (p1 <= rq - dr1);
        bool c2 = (p2 <= fmaf(-2.f, dr1, rq));
        bool c3 = (p3 <= fmaf(-3.f, dr1, rq));
        idx = 4 * qidx + (c1 ? 1 : 0) + (c2 ? 1 : 0) + (c3 ? 1 : 0);
        float Pk = c1 ? p1 : Gsel; Pk = c2 ? p2 : Pk; Pk = c3 ? p3 : Pk;
        float ek = c1 ? e1 : e0;   ek = c2 ? e2 : ek; ek = c3 ? e3 : ek;
        idxf = (float)idx;
        xk = fmaf(0.006f, idxf, -BOUND) + 5.616f * Pk * rcptot;
        wk = fmaf(5.616f * rcptot, ek, 0.006f);
        wk = (idx == 63) ? (BOUND - xk) : wk;
    }

    // ---------------- Phase 6: H logits -> exp2 -> LDS (f16, 1-term) ------
#pragma unroll
    for (int m = 0; m < 4; m++) {
        half8 a = *(const half8*)(aW3 + ((m + 4) * 64 + l) * 8);
        float4 bb = *(const float4*)(b3s + 64 + 16 * m + 4 * g);
        f32x4 binit = {bb.x, bb.y, bb.z, bb.w};
#pragma unroll
        for (int n = 0; n < 4; n++) {
            f32x4 acc = binit;
            acc = __builtin_amdgcn_mfma_f32_16x16x32_f16(a, bhi[n], acc, 0, 0, 0);
            half4 e = {(_Float16)fexp2(acc[0]), (_Float16)fexp2(acc[1]),
                       (_Float16)fexp2(acc[2]), (_Float16)fexp2(acc[3])};
            *(half4*)(bufh + (16 * n + j) * 64 +
                      (((2 * m + (g >> 1)) ^ ksw) << 3) + ((g & 1) << 2)) = e;
        }
    }

    // ---------------- Phase 7: H selection (fdot2 group sums) -------------
    float yk, hk;
    {
        int qh = idx >> 2, rh = idx & 3;
        float toth = 0.f, Gq = 0.f;
#pragma unroll
        for (int t = 0; t < 8; t++) {
            half8 hv = *(const half8*)(bufh + l * 64 + ((t ^ sx) << 3));
            half2v* hp = (half2v*)&hv;
            float gs0 = hsum2(hp[0], hsum2(hp[1], 0.f));
            float gs1 = hsum2(hp[2], hsum2(hp[3], 0.f));
            toth += gs0 + gs1;
            Gq += (2 * t < qh) ? gs0 : 0.f;
            Gq += (2 * t + 1 < qh) ? gs1 : 0.f;
        }
        half4 fv = *(const half4*)(bufh + l * 64 + (((qh >> 1) ^ sx) << 3) + ((qh & 1) << 2));
        float f0 = (float)fv[0], f1 = (float)fv[1], f2 = (float)fv[2], f3 = (float)fv[3];
        float Sh = Gq;
        Sh += (rh >= 1) ? f0 : 0.f;
        Sh += (rh >= 2) ? f1 : 0.f;
        Sh += (rh >= 3) ? f2 : 0.f;
        float x01 = (rh & 1) ? f1 : f0;
        float x23 = (rh & 1) ? f3 : f2;
        float eidx = (rh & 2) ? x23 : x01;
        float chh = 5.616f * frcp(toth);
        yk = fmaf(0.006f, idxf, -BOUND) + chh * Sh;
        hk = fmaf(chh, eidx, 0.006f);
        hk = (idx == 63) ? (BOUND - yk) : hk;
    }

    // ---------------- Phase 8: D/L via MFMA, f32-staged, 4 rounds ---------
    // Round s stages params 128+32s .. 159+32s into the 8KB buffer.
    const int c0 = (idx > 0) ? (idx - 1) : 0;
    const int rc0a = (c0 < 32) ? c0 : 31;
    const int rc0b = (c0 >= 32) ? (c0 - 32) : 0;
    const int rc1a = (idx < 32) ? idx : 31;
    const int rc1b = (idx >= 32) ? (idx - 32) : 0;
    float v0a, v0b, v1a, v1b, vl191, vla, vlb;
#pragma unroll
    for (int s = 0; s < 4; s++) {
#pragma unroll
        for (int mm = 0; mm < 2; mm++) {
            half8 a = *(const half8*)(aW3 + ((8 + 2 * s + mm) * 64 + l) * 8);
#pragma unroll
            for (int n = 0; n < 4; n++) {
                f32x4 acc = {0.f, 0.f, 0.f, 0.f};
                acc = __builtin_amdgcn_mfma_f32_16x16x32_f16(a, bhi[n], acc, 0, 0, 0);
                *(f32x4*)(buf + (16 * n + j) * 32 + (((4 * mm + g) ^ ksw) << 2)) = acc;
            }
        }
        if (s == 0) {
            v0a = buf[l * 32 + (((rc0a >> 2) ^ sx) << 2) + (rc0a & 3)];
            v1a = buf[l * 32 + (((rc1a >> 2) ^ sx) << 2) + (rc1a & 3)];
        } else if (s == 1) {
            v0b = buf[l * 32 + (((rc0b >> 2) ^ sx) << 2) + (rc0b & 3)];
            v1b = buf[l * 32 + (((rc1b >> 2) ^ sx) << 2) + (rc1b & 3)];
            vl191 = buf[l * 32 + ((7 ^ sx) << 2) + 3];   // param 191 (col 31)
        } else if (s == 2) {
            vla = buf[l * 32 + (((rc0a >> 2) ^ sx) << 2) + (rc0a & 3)];
        } else {
            vlb = buf[l * 32 + (((rc0b >> 2) ^ sx) << 2) + (rc0b & 3)];
        }
    }
    float accd0 = ((c0 < 32) ? v0a : v0b) + b3s[127 + idx];
    float accd1 = ((idx < 32) ? v1a : v1b) + b3s[(idx < 63) ? (128 + idx) : 191];
    float lsel = (c0 < 32) ? vla : vlb;
    float accl = ((idx == 0) ? vl191 : lsel) + b3s[191 + idx];

    // ---------------- Phase 9: tail ---------------------------------------
    float e0t = fexp2(-fabsf(accd0) * LOG2E);
    float sp0 = fmaxf(accd0, 0.f) + LN2 * flog2(1.f + e0t);
    float e1t = fexp2(-fabsf(accd1) * LOG2E);
    float sp1 = fmaxf(accd1, 0.f) + LN2 * flog2(1.f + e1t);
    float d0 = (idx == 0)  ? 1.f : (0.001f + sp0);
    float d1 = (idx == 63) ? 1.f : (0.001f + sp1);
    float sig = frcp(1.f + fexp2(-accl * LOG2E));
    float lam = fmaf(0.95f, sig, 0.025f);

    float rwk = frcp(wk);
    float wb = sqrtf(d0 * frcp(d1));
    float wc = fmaf(lam, d0, (1.f - lam) * wb * d1) * wk * frcp(hk);
    float ya = yk, yb = yk + hk;
    float yc = fmaf(1.f - lam, ya, lam * wb * yb) * frcp(fmaf(lam, wb, 1.f - lam));
    float theta = (xc - xk) * rwk;
    bool left = theta <= lam;
    float num = left ? fmaf(ya, lam - theta, wc * yc * theta)
                     : fmaf(wc * yc, 1.f - theta, wb * yb * (theta - lam));
    float den = left ? fmaf(wc, theta, lam - theta)
                     : fmaf(wc, 1.f - theta, wb * (theta - lam));
    float y_in = num * frcp(den);
    float dnum = left ? (wc * lam * (yc - ya))
                      : (wb * wc * (1.f - lam) * (yb - yc));
    float ld_in = LN2 * (flog2(dnum) - 2.f * flog2(fabsf(den)) - flog2(wk));

    if (gown < N) {
        out[gown]     = inside ? y_in : x;
        out[N + gown] = inside ? ld_in : 0.f;
    }
}

extern "C" void kernel_launch(void* const* d_in, const int* in_sizes, int n_in,
                              void* d_out, int out_size, void* d_ws, size_t ws_size,
                              hipStream_t stream) {
    const float* x  = (const float*)d_in[0];
    const float* cx = (const float*)d_in[1];
    const float* W1 = (const float*)d_in[2];
    const float* b1 = (const float*)d_in[3];
    const float* W2 = (const float*)d_in[4];
    const float* b2 = (const float*)d_in[5];
    const float* W3 = (const float*)d_in[6];
    const float* b3 = (const float*)d_in[7];
    int N = in_sizes[0];

    _Float16* aW3 = (_Float16*)d_ws;          // 16*64*8 halves
    _Float16* aW2 = aW3 + 16 * 64 * 8;        // 1024 halves
    float* b3s = (float*)(aW2 + 2 * 64 * 8);  // 255 floats
    float* out = (float*)d_out;

    hipLaunchKernelGGL(prep_kernel, dim3(8), dim3(256), 0, stream, W2, W3, b3, aW2, aW3, b3s);
    hipLaunchKernelGGL(spline_kernel, dim3((N + 127) / 128), dim3(128), 0, stream,
                       x, cx, W1, b1, b2, b3s, aW2, aW3, out, N);
}

// Round 11
// 59.561 us; speedup vs baseline: 1.9126x; 1.0131x over previous
//
#include <hip/hip_runtime.h>
#include <math.h>

#define BOUND 3.0f
#define LOG2E 1.4426950408889634f
#define LN2 0.6931471805599453f
#define CINV 0.17806267806267807f   /* 1/5.616 */

typedef _Float16 half8 __attribute__((ext_vector_type(8)));
typedef _Float16 half4 __attribute__((ext_vector_type(4)));
typedef _Float16 half2v __attribute__((ext_vector_type(2)));
typedef float f32x4 __attribute__((ext_vector_type(4)));
typedef float f32x2 __attribute__((ext_vector_type(2)));

__device__ __forceinline__ float fexp2(float x) { return __builtin_amdgcn_exp2f(x); }
__device__ __forceinline__ float flog2(float x) { return __builtin_amdgcn_logf(x); }
__device__ __forceinline__ float frcp(float x)  { return __builtin_amdgcn_rcpf(x); }

__device__ __forceinline__ float hsum2(half2v a, float c) {
    const half2v ones = {(_Float16)1.f, (_Float16)1.f};
    return __builtin_amdgcn_fdot2(a, ones, c, false);
}

// packed f32 -> 2xf16 (RTZ), bit-cast from the builtin's __fp16 vector type.
// hi-term rounding mode is irrelevant for the 2-term split (lo captures the
// residual); RTZ halves the cvt inst count.
__device__ __forceinline__ half2v pkcvt(float a, float b) {
    return __builtin_bit_cast(half2v, __builtin_amdgcn_cvt_pkrtz(a, b));
}

// A-fragments for transposed GEMM C[param][elem], 16x16x32 f16.
// aW3[m][l][t] = W3[8*(l>>4)+t][16m + (l&15)] * (m<8 ? LOG2E : 1)
__global__ void prep_kernel(const float* __restrict__ W2, const float* __restrict__ W3,
                            const float* __restrict__ b3,
                            _Float16* __restrict__ aW2, _Float16* __restrict__ aW3,
                            float* __restrict__ b3s) {
    int tid = blockIdx.x * blockDim.x + threadIdx.x;
    int nth = gridDim.x * blockDim.x;
    for (int i = tid; i < 16 * 64 * 8; i += nth) {
        int t = i & 7, l = (i >> 3) & 63, m = i >> 9;
        int k = 8 * (l >> 4) + t, col = 16 * m + (l & 15);
        float v = (col < 255) ? W3[k * 255 + col] : 0.f;
        if (m < 8) v *= LOG2E;
        aW3[i] = (_Float16)v;
    }
    for (int i = tid; i < 2 * 64 * 8; i += nth) {
        int t = i & 7, l = (i >> 3) & 63, m = i >> 9;
        int k = 8 * (l >> 4) + t, col = 16 * m + (l & 15);
        aW2[i] = (_Float16)W2[k * 32 + col];
    }
    for (int i = tid; i < 255; i += nth)
        b3s[i] = b3[i] * ((i < 128) ? LOG2E : 1.f);
}

// R6 packaging (best known: 59.4us): 64-thread 1-wave WGs, 8KB LDS,
// (64,4) -> natural VGPR 64, no barriers anywhere.
__global__ __launch_bounds__(64, 4) void spline_kernel(
    const float* __restrict__ x_in, const float* __restrict__ cond_in,
    const float* __restrict__ W1, const float* __restrict__ b1,
    const float* __restrict__ b2, const float* __restrict__ b3s,
    const _Float16* __restrict__ aW2, const _Float16* __restrict__ aW3,
    float* __restrict__ out, int N) {

    //  f32 view: 64 rows x 32 f32 (128B rows, 8 granules, XOR-swizzled)
    //  f16 view: 64 rows x 64 halves (128B rows, 8 granules, XOR-swizzled)
    __shared__ float sbuf[64 * 32];

    const int l = threadIdx.x;
    const int j = l & 15, g = l >> 4;
    const int sx = l & 7;
    const int ksw = j & 7;
    const int gown = blockIdx.x * 64 + l;
    const int ic = (gown < N) ? gown : (N - 1);

    float* buf = sbuf;
    _Float16* bufh = (_Float16*)sbuf;

    float cx = cond_in[ic];
    float x = x_in[ic];

    // ---------------- Phase 1: h1 B-fragments (rank-1, packed f32) --------
    f32x2 w1p[4], b1p[4];
#pragma unroll
    for (int p = 0; p < 4; p++) {
        w1p[p] = *(const f32x2*)(W1 + 8 * g + 2 * p);
        b1p[p] = *(const f32x2*)(b1 + 8 * g + 2 * p);
    }

    half8 h1hi[4], h1lo[4];
#pragma unroll
    for (int n = 0; n < 4; n++) {
        float c = __shfl(cx, 16 * n + j, 64);
        f32x2 c2 = {c, c};
        const f32x2 z2 = {0.f, 0.f};
#pragma unroll
        for (int p = 0; p < 4; p++) {
            f32x2 h = c2 * w1p[p] + b1p[p];          // v_pk_fma_f32
            h = __builtin_elementwise_max(h, z2);    // v_pk_max_f32
            half2v hi = pkcvt(h.x, h.y);
            f32x2 hf = {(float)hi[0], (float)hi[1]};
            f32x2 lo = h - hf;                       // v_pk_add_f32
            half2v lov = pkcvt(lo.x, lo.y);
            h1hi[n][2 * p] = hi[0];  h1hi[n][2 * p + 1] = hi[1];
            h1lo[n][2 * p] = lov[0]; h1lo[n][2 * p + 1] = lov[1];
        }
    }

    // ---------------- Phase 2: MLP2 via MFMA, split h2 -> LDS (f16) -------
    half8 a2[2];
    a2[0] = *(const half8*)(aW2 + (0 * 64 + l) * 8);
    a2[1] = *(const half8*)(aW2 + (1 * 64 + l) * 8);

#pragma unroll
    for (int m = 0; m < 2; m++) {
        float4 bb = *(const float4*)(b2 + 16 * m + 4 * g);
        f32x4 binit = {bb.x, bb.y, bb.z, bb.w};
#pragma unroll
        for (int n = 0; n < 4; n++) {
            f32x4 acc = binit;
            acc = __builtin_amdgcn_mfma_f32_16x16x32_f16(a2[m], h1lo[n], acc, 0, 0, 0);
            acc = __builtin_amdgcn_mfma_f32_16x16x32_f16(a2[m], h1hi[n], acc, 0, 0, 0);
            const f32x2 z2 = {0.f, 0.f};
            f32x2 v01 = {acc[0], acc[1]}, v23 = {acc[2], acc[3]};
            v01 = __builtin_elementwise_max(v01, z2);
            v23 = __builtin_elementwise_max(v23, z2);
            half2v h01 = pkcvt(v01.x, v01.y);
            half2v h23 = pkcvt(v23.x, v23.y);
            f32x2 f01 = {(float)h01[0], (float)h01[1]};
            f32x2 f23 = {(float)h23[0], (float)h23[1]};
            f32x2 l01 = v01 - f01, l23 = v23 - f23;
            half2v q01 = pkcvt(l01.x, l01.y);
            half2v q23 = pkcvt(l23.x, l23.y);
            half4 hv = {h01[0], h01[1], h23[0], h23[1]};
            half4 lv = {q01[0], q01[1], q23[0], q23[1]};
            int rb = (16 * n + j) * 64;
            *(half4*)(bufh + rb + (((2 * m + (g >> 1)) ^ ksw) << 3) + ((g & 1) << 2)) = hv;
            *(half4*)(bufh + rb + (((4 + 2 * m + (g >> 1)) ^ ksw) << 3) + ((g & 1) << 2)) = lv;
        }
    }

    // ---------------- Phase 3: h2 B-fragments -----------------------------
    half8 bhi[4], blo[4];
#pragma unroll
    for (int n = 0; n < 4; n++) {
        int rb = (16 * n + j) * 64;
        bhi[n] = *(const half8*)(bufh + rb + ((g ^ ksw) << 3));
        blo[n] = *(const half8*)(bufh + rb + (((4 + g) ^ ksw) << 3));
    }

    bool inside = (x >= -BOUND) && (x <= BOUND);
    float xc = fminf(fmaxf(x, -BOUND), BOUND);

    // ---------------- Phase 4: W logits -> exp2 -> LDS (f32, 2 rounds) ----
    f32x4 wv[16];
#pragma unroll
    for (int s = 0; s < 2; s++) {
#pragma unroll
        for (int mm = 0; mm < 2; mm++) {
            int m = 2 * s + mm;
            half8 a = *(const half8*)(aW3 + (m * 64 + l) * 8);
            float4 bb = *(const float4*)(b3s + 16 * m + 4 * g);
            f32x4 binit = {bb.x, bb.y, bb.z, bb.w};
#pragma unroll
            for (int n = 0; n < 4; n++) {
                f32x4 acc = binit;
                acc = __builtin_amdgcn_mfma_f32_16x16x32_f16(a, blo[n], acc, 0, 0, 0);
                acc = __builtin_amdgcn_mfma_f32_16x16x32_f16(a, bhi[n], acc, 0, 0, 0);
                f32x4 e = {fexp2(acc[0]), fexp2(acc[1]), fexp2(acc[2]), fexp2(acc[3])};
                *(f32x4*)(buf + (16 * n + j) * 32 + (((4 * mm + g) ^ ksw) << 2)) = e;
            }
        }
#pragma unroll
        for (int t = 0; t < 8; t++)
            wv[8 * s + t] = *(const f32x4*)(buf + l * 32 + ((t ^ sx) << 2));
    }

    // ---------------- Phase 5: hierarchical W scan (f32-exact) ------------
    int idx; float idxf, xk, wk;
    {
        float G[16];
        float run = 0.f;
#pragma unroll
        for (int t = 0; t < 16; t++) {
            run += (wv[t][0] + wv[t][1]) + (wv[t][2] + wv[t][3]);
            G[t] = run;
        }
        float tot = G[15];
        float rcptot = frcp(tot);
        float rr = (xc + BOUND) * tot * CINV;
        float dr1 = 0.0010683761f * tot;
        float dr4 = 4.f * dr1;
        float r = rr, Gsel = 0.f;
        int qidx = 0;
#pragma unroll
        for (int t = 0; t < 15; t++) {
            r -= dr4;
            bool c = (G[t] <= r);
            qidx += c ? 1 : 0;
            Gsel = c ? G[t] : Gsel;
        }
        f32x4 fv = wv[0];
#pragma unroll
        for (int t = 1; t < 16; t++) fv = (qidx == t) ? wv[t] : fv;
        float e0 = fv[0], e1 = fv[1], e2 = fv[2], e3 = fv[3];
        float qf = (float)qidx;
        float rq = fmaf(-qf, dr4, rr);
        float p1 = Gsel + e0, p2 = p1 + e1, p3 = p2 + e2;
        bool c1 = (p1 <= rq - dr1);
        bool c2 = (p2 <= fmaf(-2.f, dr1, rq));
        bool c3 = (p3 <= fmaf(-3.f, dr1, rq));
        idx = 4 * qidx + (c1 ? 1 : 0) + (c2 ? 1 : 0) + (c3 ? 1 : 0);
        float Pk = c1 ? p1 : Gsel; Pk = c2 ? p2 : Pk; Pk = c3 ? p3 : Pk;
        float ek = c1 ? e1 : e0;   ek = c2 ? e2 : ek; ek = c3 ? e3 : ek;
        idxf = (float)idx;
        xk = fmaf(0.006f, idxf, -BOUND) + 5.616f * Pk * rcptot;
        wk = fmaf(5.616f * rcptot, ek, 0.006f);
        wk = (idx == 63) ? (BOUND - xk) : wk;
    }

    // ---------------- Phase 6: H logits -> exp2 -> LDS (f16, 1-term) ------
#pragma unroll
    for (int m = 0; m < 4; m++) {
        half8 a = *(const half8*)(aW3 + ((m + 4) * 64 + l) * 8);
        float4 bb = *(const float4*)(b3s + 64 + 16 * m + 4 * g);
        f32x4 binit = {bb.x, bb.y, bb.z, bb.w};
#pragma unroll
        for (int n = 0; n < 4; n++) {
            f32x4 acc = binit;
            acc = __builtin_amdgcn_mfma_f32_16x16x32_f16(a, bhi[n], acc, 0, 0, 0);
            half2v e01 = pkcvt(fexp2(acc[0]), fexp2(acc[1]));
            half2v e23 = pkcvt(fexp2(acc[2]), fexp2(acc[3]));
            half4 e = {e01[0], e01[1], e23[0], e23[1]};
            *(half4*)(bufh + (16 * n + j) * 64 +
                      (((2 * m + (g >> 1)) ^ ksw) << 3) + ((g & 1) << 2)) = e;
        }
    }

    // ---------------- Phase 7: H selection (fdot2 group sums) -------------
    float yk, hk;
    {
        int qh = idx >> 2, rh = idx & 3;
        float toth = 0.f, Gq = 0.f;
#pragma unroll
        for (int t = 0; t < 8; t++) {
            half8 hv = *(const half8*)(bufh + l * 64 + ((t ^ sx) << 3));
            half2v* hp = (half2v*)&hv;
            float gs0 = hsum2(hp[0], hsum2(hp[1], 0.f));
            float gs1 = hsum2(hp[2], hsum2(hp[3], 0.f));
            toth += gs0 + gs1;
            Gq += (2 * t < qh) ? gs0 : 0.f;
            Gq += (2 * t + 1 < qh) ? gs1 : 0.f;
        }
        half4 fv = *(const half4*)(bufh + l * 64 + (((qh >> 1) ^ sx) << 3) + ((qh & 1) << 2));
        float f0 = (float)fv[0], f1 = (float)fv[1], f2 = (float)fv[2], f3 = (float)fv[3];
        float Sh = Gq;
        Sh += (rh >= 1) ? f0 : 0.f;
        Sh += (rh >= 2) ? f1 : 0.f;
        Sh += (rh >= 3) ? f2 : 0.f;
        float x01 = (rh & 1) ? f1 : f0;
        float x23 = (rh & 1) ? f3 : f2;
        float eidx = (rh & 2) ? x23 : x01;
        float chh = 5.616f * frcp(toth);
        yk = fmaf(0.006f, idxf, -BOUND) + chh * Sh;
        hk = fmaf(chh, eidx, 0.006f);
        hk = (idx == 63) ? (BOUND - yk) : hk;
    }

    // ---------------- Phase 8: D/L via MFMA, f32-staged, 4 rounds ---------
    // Round s stages params 128+32s .. 159+32s into the 8KB buffer.
    const int c0 = (idx > 0) ? (idx - 1) : 0;
    const int rc0a = (c0 < 32) ? c0 : 31;
    const int rc0b = (c0 >= 32) ? (c0 - 32) : 0;
    const int rc1a = (idx < 32) ? idx : 31;
    const int rc1b = (idx >= 32) ? (idx - 32) : 0;
    float v0a, v0b, v1a, v1b, vl191, vla, vlb;
#pragma unroll
    for (int s = 0; s < 4; s++) {
#pragma unroll
        for (int mm = 0; mm < 2; mm++) {
            half8 a = *(const half8*)(aW3 + ((8 + 2 * s + mm) * 64 + l) * 8);
#pragma unroll
            for (int n = 0; n < 4; n++) {
                f32x4 acc = {0.f, 0.f, 0.f, 0.f};
                acc = __builtin_amdgcn_mfma_f32_16x16x32_f16(a, bhi[n], acc, 0, 0, 0);
                *(f32x4*)(buf + (16 * n + j) * 32 + (((4 * mm + g) ^ ksw) << 2)) = acc;
            }
        }
        if (s == 0) {
            v0a = buf[l * 32 + (((rc0a >> 2) ^ sx) << 2) + (rc0a & 3)];
            v1a = buf[l * 32 + (((rc1a >> 2) ^ sx) << 2) + (rc1a & 3)];
        } else if (s == 1) {
            v0b = buf[l * 32 + (((rc0b >> 2) ^ sx) << 2) + (rc0b & 3)];
            v1b = buf[l * 32 + (((rc1b >> 2) ^ sx) << 2) + (rc1b & 3)];
            vl191 = buf[l * 32 + ((7 ^ sx) << 2) + 3];   // param 191 (col 31)
        } else if (s == 2) {
            vla = buf[l * 32 + (((rc0a >> 2) ^ sx) << 2) + (rc0a & 3)];
        } else {
            vlb = buf[l * 32 + (((rc0b >> 2) ^ sx) << 2) + (rc0b & 3)];
        }
    }
    float accd0 = ((c0 < 32) ? v0a : v0b) + b3s[127 + idx];
    float accd1 = ((idx < 32) ? v1a : v1b) + b3s[(idx < 63) ? (128 + idx) : 191];
    float lsel = (c0 < 32) ? vla : vlb;
    float accl = ((idx == 0) ? vl191 : lsel) + b3s[191 + idx];

    // ---------------- Phase 9: tail ---------------------------------------
    float e0t = fexp2(-fabsf(accd0) * LOG2E);
    float sp0 = fmaxf(accd0, 0.f) + LN2 * flog2(1.f + e0t);
    float e1t = fexp2(-fabsf(accd1) * LOG2E);
    float sp1 = fmaxf(accd1, 0.f) + LN2 * flog2(1.f + e1t);
    float d0 = (idx == 0)  ? 1.f : (0.001f + sp0);
    float d1 = (idx == 63) ? 1.f : (0.001f + sp1);
    float sig = frcp(1.f + fexp2(-accl * LOG2E));
    float lam = fmaf(0.95f, sig, 0.025f);

    float rwk = frcp(wk);
    float wb = sqrtf(d0 * frcp(d1));
    float wc = fmaf(lam, d0, (1.f - lam) * wb * d1) * wk * frcp(hk);
    float ya = yk, yb = yk + hk;
    float yc = fmaf(1.f - lam, ya, lam * wb * yb) * frcp(fmaf(lam, wb, 1.f - lam));
    float theta = (xc - xk) * rwk;
    bool left = theta <= lam;
    float num = left ? fmaf(ya, lam - theta, wc * yc * theta)
                     : fmaf(wc * yc, 1.f - theta, wb * yb * (theta - lam));
    float den = left ? fmaf(wc, theta, lam - theta)
                     : fmaf(wc, 1.f - theta, wb * (theta - lam));
    float y_in = num * frcp(den);
    float dnum = left ? (wc * lam * (yc - ya))
                      : (wb * wc * (1.f - lam) * (yb - yc));
    float ld_in = LN2 * (flog2(dnum) - 2.f * flog2(fabsf(den)) - flog2(wk));

    if (gown < N) {
        out[gown]     = inside ? y_in : x;
        out[N + gown] = inside ? ld_in : 0.f;
    }
}

extern "C" void kernel_launch(void* const* d_in, const int* in_sizes, int n_in,
                              void* d_out, int out_size, void* d_ws, size_t ws_size,
                              hipStream_t stream) {
    const float* x  = (const float*)d_in[0];
    const float* cx = (const float*)d_in[1];
    const float* W1 = (const float*)d_in[2];
    const float* b1 = (const float*)d_in[3];
    const float* W2 = (const float*)d_in[4];
    const float* b2 = (const float*)d_in[5];
    const float* W3 = (const float*)d_in[6];
    const float* b3 = (const float*)d_in[7];
    int N = in_sizes[0];

    _Float16* aW3 = (_Float16*)d_ws;          // 16*64*8 halves
    _Float16* aW2 = aW3 + 16 * 64 * 8;        // 1024 halves
    float* b3s = (float*)(aW2 + 2 * 64 * 8);  // 255 floats
    float* out = (float*)d_out;

    hipLaunchKernelGGL(prep_kernel, dim3(8), dim3(256), 0, stream, W2, W3, b3, aW2, aW3, b3s);
    hipLaunchKernelGGL(spline_kernel, dim3((N + 63) / 64), dim3(64), 0, stream,
                       x, cx, W1, b1, b2, b3s, aW2, aW3, out, N);
}